// Round 1
// 441.162 us; speedup vs baseline: 1.0286x; 1.0286x over previous
//
#include <hip/hip_runtime.h>
#include <hip/hip_bf16.h>
#include <cstdint>
#include <cstddef>

using bf16 = __hip_bfloat16;
using short4v = __attribute__((ext_vector_type(4))) short;  // 4 bf16 (2 VGPRs)
using short8 = __attribute__((ext_vector_type(8))) short;   // 8 bf16 (4 VGPRs)
using floatx4 = __attribute__((ext_vector_type(4))) float;  // MFMA C/D frag

#define MFMA_BF16(A, B, C) __builtin_amdgcn_mfma_f32_16x16x32_bf16((A), (B), (C), 0, 0, 0)

__device__ inline short bf16_bits(float x) {
  bf16 v = __float2bfloat16(x);
  short r;
  __builtin_memcpy(&r, &v, 2);
  return r;
}

__device__ inline void store_c(bf16* p, float v) { *p = __float2bfloat16(v); }
__device__ inline void store_c(float* p, float v) { *p = v; }

// ---------------------------------------------------------------------------
// f32 -> bf16 bulk convert (RNE). 8 elements/thread, 16B stores.
// ---------------------------------------------------------------------------
__global__ __launch_bounds__(256) void f32_to_bf16_kernel(
    const float* __restrict__ src, bf16* __restrict__ dst, int n8) {
  const int i = blockIdx.x * 256 + threadIdx.x;
  if (i >= n8) return;
  const float4 a = ((const float4*)src)[2 * i];
  const float4 b = ((const float4*)src)[2 * i + 1];
  short8 r;
  r[0] = bf16_bits(a.x); r[1] = bf16_bits(a.y); r[2] = bf16_bits(a.z); r[3] = bf16_bits(a.w);
  r[4] = bf16_bits(b.x); r[5] = bf16_bits(b.y); r[6] = bf16_bits(b.z); r[7] = bf16_bits(b.w);
  *(short8*)(dst + (size_t)i * 8) = r;
}

// ---------------------------------------------------------------------------
// GEMM (m97 structure): C[m,n] = sum_k A[m,k]*B[n,k], A,B row-major bf16,
// row stride K; C row-major stride ldc. Tile 128x128, BK=64, 4 waves (2x2).
// global_load_lds width=16 staging with XOR chunk swizzle.
// ---------------------------------------------------------------------------
template <typename TC>
__global__ __launch_bounds__(256) void gemm_bt_async(
    const bf16* __restrict__ A, const bf16* __restrict__ B, TC* __restrict__ C,
    int ldc, int K) {
  __shared__ bf16 As[128 * 64];
  __shared__ bf16 Bs[128 * 64];
  const int tid = threadIdx.x;
  const int lane = tid & 63;
  const int wave = tid >> 6;
  const int lrow = lane & 15;
  const int quad = lane >> 4;
  const int wm = (wave >> 1) * 64;
  const int wn = (wave & 1) * 64;
  const int tm = blockIdx.y * 128;
  const int tn = blockIdx.x * 128;

  const int srow = tid >> 3;
  const int scl = tid & 7;

  floatx4 acc[4][4] = {};

  for (int k0 = 0; k0 < K; k0 += 64) {
    __syncthreads();
#pragma unroll
    for (int r = 0; r < 4; ++r) {
      const int row = r * 32 + srow;
      const int scg = scl ^ (row & 7);
      __builtin_amdgcn_global_load_lds(
          (const __attribute__((address_space(1))) void*)(A + (size_t)(tm + row) * K + k0 + scg * 8),
          (__attribute__((address_space(3))) void*)(As + row * 64 + scl * 8), 16, 0, 0);
    }
#pragma unroll
    for (int r = 0; r < 4; ++r) {
      const int row = r * 32 + srow;
      const int scg = scl ^ (row & 7);
      __builtin_amdgcn_global_load_lds(
          (const __attribute__((address_space(1))) void*)(B + (size_t)(tn + row) * K + k0 + scg * 8),
          (__attribute__((address_space(3))) void*)(Bs + row * 64 + scl * 8), 16, 0, 0);
    }
    __syncthreads();

#pragma unroll
    for (int kk = 0; kk < 2; ++kk) {
      short8 af[4], bfr[4];
#pragma unroll
      for (int i = 0; i < 4; ++i) {
        const int ra = wm + i * 16 + lrow;
        const int rb = wn + i * 16 + lrow;
        af[i] = *(const short8*)&As[ra * 64 + (((kk * 4 + quad) ^ (ra & 7)) * 8)];
        bfr[i] = *(const short8*)&Bs[rb * 64 + (((kk * 4 + quad) ^ (rb & 7)) * 8)];
      }
#pragma unroll
      for (int i = 0; i < 4; ++i)
#pragma unroll
        for (int j = 0; j < 4; ++j)
          acc[i][j] = MFMA_BF16(af[i], bfr[j], acc[i][j]);
    }
  }

#pragma unroll
  for (int i = 0; i < 4; ++i)
#pragma unroll
    for (int j = 0; j < 4; ++j)
#pragma unroll
      for (int r = 0; r < 4; ++r) {
        const int row = tm + wm + i * 16 + quad * 4 + r;
        const int col = tn + wn + j * 16 + lrow;
        store_c(&C[(size_t)row * ldc + col], acc[i][j][r]);
      }
}

// ---------------------------------------------------------------------------
// Mixed GEMM for the out-projection: A bf16 via global_load_lds; B f32 weight
// via register prefetch + convert + swizzled ds_write. C f32.
// ---------------------------------------------------------------------------
__global__ __launch_bounds__(256) void gemm_abf16_bf32(
    const bf16* __restrict__ A, const float* __restrict__ B, float* __restrict__ C,
    int ldc, int K) {
  __shared__ bf16 As[128 * 64];
  __shared__ bf16 Bs[128 * 64];
  const int tid = threadIdx.x;
  const int lane = tid & 63;
  const int wave = tid >> 6;
  const int lrow = lane & 15;
  const int quad = lane >> 4;
  const int wm = (wave >> 1) * 64;
  const int wn = (wave & 1) * 64;
  const int tm = blockIdx.y * 128;
  const int tn = blockIdx.x * 128;

  const int srow = tid >> 3;
  const int scl = tid & 7;
  const int c16 = tid & 15;
  const int br0 = tid >> 4;

  floatx4 acc[4][4] = {};
  float4 breg[8];
#pragma unroll
  for (int r = 0; r < 8; ++r)
    breg[r] = *(const float4*)(B + (size_t)(tn + r * 16 + br0) * K + c16 * 4);

  for (int k0 = 0; k0 < K; k0 += 64) {
    __syncthreads();
#pragma unroll
    for (int r = 0; r < 4; ++r) {
      const int row = r * 32 + srow;
      const int scg = scl ^ (row & 7);
      __builtin_amdgcn_global_load_lds(
          (const __attribute__((address_space(1))) void*)(A + (size_t)(tm + row) * K + k0 + scg * 8),
          (__attribute__((address_space(3))) void*)(As + row * 64 + scl * 8), 16, 0, 0);
    }
#pragma unroll
    for (int r = 0; r < 8; ++r) {
      const int row = r * 16 + br0;
      short4v sv;
      sv[0] = bf16_bits(breg[r].x); sv[1] = bf16_bits(breg[r].y);
      sv[2] = bf16_bits(breg[r].z); sv[3] = bf16_bits(breg[r].w);
      *(short4v*)&Bs[row * 64 + (((c16 >> 1) ^ (row & 7)) * 8) + (c16 & 1) * 4] = sv;
    }
    __syncthreads();
    if (k0 + 64 < K) {
#pragma unroll
      for (int r = 0; r < 8; ++r)
        breg[r] = *(const float4*)(B + (size_t)(tn + r * 16 + br0) * K + k0 + 64 + c16 * 4);
    }

#pragma unroll
    for (int kk = 0; kk < 2; ++kk) {
      short8 af[4], bfr[4];
#pragma unroll
      for (int i = 0; i < 4; ++i) {
        const int ra = wm + i * 16 + lrow;
        const int rb = wn + i * 16 + lrow;
        af[i] = *(const short8*)&As[ra * 64 + (((kk * 4 + quad) ^ (ra & 7)) * 8)];
        bfr[i] = *(const short8*)&Bs[rb * 64 + (((kk * 4 + quad) ^ (rb & 7)) * 8)];
      }
#pragma unroll
      for (int i = 0; i < 4; ++i)
#pragma unroll
        for (int j = 0; j < 4; ++j)
          acc[i][j] = MFMA_BF16(af[i], bfr[j], acc[i][j]);
    }
  }

#pragma unroll
  for (int i = 0; i < 4; ++i)
#pragma unroll
    for (int j = 0; j < 4; ++j)
#pragma unroll
      for (int r = 0; r < 4; ++r) {
        const int row = tm + wm + i * 16 + quad * 4 + r;
        const int col = tn + wn + j * 16 + lrow;
        C[(size_t)row * ldc + col] = acc[i][j][r];
      }
}

// ---------------------------------------------------------------------------
// RoPE, in-place on bf16 qkv. One thread per (b,s,h,q/k,pair).
// ---------------------------------------------------------------------------
__global__ void rope_kernel(bf16* __restrict__ qkv) {
  const int idx = blockIdx.x * 256 + threadIdx.x;
  const int i = idx & 15;
  int t = idx >> 4;
  const int qk = t & 1;
  t >>= 1;
  const int h = t & 15;
  t >>= 4;
  const int s = t & 2047;
  bf16* p = qkv + (size_t)t * 6144 + (h >> 1) * 768 + (h & 1) * 128 + qk * 256 + 2 * i;
  const float x0 = __bfloat162float(p[0]);
  const float x1 = __bfloat162float(p[1]);
  const float inv = powf(10000.f, -(float)(2 * i) / 32.f);
  const float ang = (float)s * inv;
  float sn, cs;
  sincosf(ang, &sn, &cs);
  p[0] = __float2bfloat16(x0 * cs - x1 * sn);
  p[1] = __float2bfloat16(x1 * cs + x0 * sn);
}

// ---------------------------------------------------------------------------
// Flash attention — latency-hiding revision of the round-4 proven internals.
//   * q-tile 64 rows (wave owns 16 rows), grid (16,H,B) = 512 blocks
//     -> 2 independent blocks/CU (LDS 40KB/block), doubles occupancy.
//   * causal work pairing: phase 0 qb=bx, phase 1 qb=31-bx -> 33 k-iters/blk.
//   * async-STAGE split (T14): next K/V tile global->reg loads issued right
//     after the stage barrier; reg->LDS write happens after the next
//     top-of-loop barrier, so HBM latency hides under QK^T/softmax/PV.
//   * P barrier removed: Ps rows are written AND read by the same wave
//     (write rows wave*16+quad*4+r, read rows wave*16+lrow) -> within-wave
//     LDS RAW, lgkmcnt suffices. 2 barriers/iter instead of 3.
//   * causal mask only evaluated on the diagonal k-block (uniform branch).
//   * s_setprio(1) around MFMA clusters (m191: +4-7% on attn).
// Internals otherwise identical to the proven kernel: per 64-key block
// register-staged K (B-frag layout) and V-transposed in LDS; S = Q K^T via
// MFMA; scale + mask + online softmax (16-lane shuffle reductions over
// C-layout rows); P -> LDS (A-frag layout); O += P V via MFMA.
// ---------------------------------------------------------------------------
__global__ __launch_bounds__(256) void attn_flash_pair(
    const bf16* __restrict__ qkv, bf16* __restrict__ out) {
  __shared__ short Ks[16 * 64 * 8];  // [d/8][sk][8]          16 KB
  __shared__ short Vs[8 * 128 * 8];  // [sk/8][d][8] (V^T)    16 KB
  __shared__ short Ps[8 * 64 * 8];   // [sk/8][qrow][8]        8 KB
  const int tid = threadIdx.x;
  const int wave = tid >> 6;
  const int lane = tid & 63;
  const int lrow = lane & 15;
  const int quad = lane >> 4;
  const int h = blockIdx.y;
  const int b = blockIdx.z;
  const size_t SROW = 6144;
  const bf16* base = qkv + (size_t)b * 2048 * SROW;
  const int qoff = (h >> 1) * 768 + (h & 1) * 128;
  const int koff = qoff + 256;
  const int voff = qoff + 512;
  const float scale = 0.088388347648318447f;  // 1/sqrt(128)

  const int sr = tid >> 2;  // staging row 0..63
  const int sq = tid & 3;   // staging quarter of the 128-wide d strip

  const bf16* kbase = base + (size_t)sr * SROW + koff + sq * 32;
  const bf16* vbase = base + (size_t)sr * SROW + voff + sq * 8;

  // Prefetch k-block 0 into registers (valid for both phases: K/V addresses
  // do not depend on qb).
  short8 kv[4], vv[4];
#pragma unroll
  for (int j = 0; j < 4; ++j) kv[j] = *(const short8*)(kbase + j * 8);
#pragma unroll
  for (int i = 0; i < 4; ++i) vv[i] = *(const short8*)(vbase + i * 32);

  for (int phase = 0; phase < 2; ++phase) {
    const int qb = phase ? (31 - (int)blockIdx.x) : (int)blockIdx.x;

    // Q A-frags: rows qb*64 + wave*16 + lrow, d = ks*32 + quad*8 + j
    short8 qf[4];
    {
      const bf16* qp = base + (size_t)(qb * 64 + wave * 16 + lrow) * SROW + qoff + quad * 8;
#pragma unroll
      for (int ks = 0; ks < 4; ++ks) qf[ks] = *(const short8*)(qp + ks * 32);
    }

    floatx4 o[8] = {};
    float m_i[4], l_i[4];
#pragma unroll
    for (int i = 0; i < 4; ++i) {
      m_i[i] = -1e30f;
      l_i[i] = 0.f;
    }

    const int kb_end = qb + 1;  // causal: only k-blocks overlapping tril
    for (int kb = 0; kb < kb_end; ++kb) {
      __syncthreads();  // all waves done reading Ks/Vs (prev iter or prev phase)

      // reg -> LDS stage of the prefetched tile
#pragma unroll
      for (int j = 0; j < 4; ++j) *(short8*)&Ks[((sq * 4 + j) * 64 + sr) * 8] = kv[j];
      {
        const int so = (sr >> 3) * 128, si = sr & 7;
#pragma unroll
        for (int i = 0; i < 4; ++i) {
          const int d0 = sq * 8 + i * 32;
#pragma unroll
          for (int j = 0; j < 8; ++j) Vs[(so + d0 + j) * 8 + si] = vv[i][j];
        }
      }
      __syncthreads();

      // Issue next tile's global loads now; they complete during compute and
      // are consumed by the reg->LDS stage after the next barrier.
      {
        const bool pf = (kb + 1 < kb_end) || (phase == 0);
        const int nkb = (kb + 1 < kb_end) ? kb + 1 : 0;  // phase-0 tail preloads kb=0 for phase 1
        if (pf) {
          const size_t off = (size_t)nkb * 64 * SROW;
#pragma unroll
          for (int j = 0; j < 4; ++j) kv[j] = *(const short8*)(kbase + off + j * 8);
#pragma unroll
          for (int i = 0; i < 4; ++i) vv[i] = *(const short8*)(vbase + off + i * 32);
        }
      }

      // S = Q K^T  (rows: wave's 16 q-rows; cols: 64 keys)
      floatx4 sc[4] = {};
      __builtin_amdgcn_s_setprio(1);
#pragma unroll
      for (int ks = 0; ks < 4; ++ks) {
        short8 bfr[4];
#pragma unroll
        for (int ct = 0; ct < 4; ++ct)
          bfr[ct] = *(const short8*)&Ks[((ks * 4 + quad) * 64 + ct * 16 + lrow) * 8];
#pragma unroll
        for (int ct = 0; ct < 4; ++ct)
          sc[ct] = MFMA_BF16(qf[ks], bfr[ct], sc[ct]);
      }
      __builtin_amdgcn_s_setprio(0);

      // scale + causal mask (diagonal block only) + online softmax
      const bool diag = (kb == qb);
#pragma unroll
      for (int r = 0; r < 4; ++r) {
        const int row_g = qb * 64 + wave * 16 + quad * 4 + r;
        float mx = -1e30f;
#pragma unroll
        for (int ct = 0; ct < 4; ++ct) {
          float v = sc[ct][r] * scale;
          if (diag) {
            const int col_g = kb * 64 + ct * 16 + lrow;
            if (col_g > row_g) v = -1e9f;
          }
          sc[ct][r] = v;
          mx = fmaxf(mx, v);
        }
#pragma unroll
        for (int off = 1; off < 16; off <<= 1) mx = fmaxf(mx, __shfl_xor(mx, off, 64));
        const float mnew = fmaxf(m_i[r], mx);
        const float alpha = __expf(m_i[r] - mnew);
        m_i[r] = mnew;
        float rs = 0.f;
#pragma unroll
        for (int ct = 0; ct < 4; ++ct) {
          const float p = __expf(sc[ct][r] - mnew);
          sc[ct][r] = p;
          rs += p;
        }
#pragma unroll
        for (int off = 1; off < 16; off <<= 1) rs += __shfl_xor(rs, off, 64);
        l_i[r] = l_i[r] * alpha + rs;
#pragma unroll
        for (int dt = 0; dt < 8; ++dt) o[dt][r] *= alpha;
      }

      // P (bf16) -> LDS in A-frag layout. No barrier: each wave writes and
      // reads only its own 16 q-rows of Ps (within-wave LDS RAW).
#pragma unroll
      for (int ct = 0; ct < 4; ++ct)
#pragma unroll
        for (int r = 0; r < 4; ++r) {
          const int row_l = wave * 16 + quad * 4 + r;
          const int sk = ct * 16 + lrow;
          Ps[((sk >> 3) * 64 + row_l) * 8 + (sk & 7)] = bf16_bits(sc[ct][r]);
        }

      // O += P V
      __builtin_amdgcn_s_setprio(1);
#pragma unroll
      for (int ks = 0; ks < 2; ++ks) {
        short8 af = *(const short8*)&Ps[((ks * 4 + quad) * 64 + wave * 16 + lrow) * 8];
        short8 bfr[8];
#pragma unroll
        for (int dt = 0; dt < 8; ++dt)
          bfr[dt] = *(const short8*)&Vs[((ks * 4 + quad) * 128 + dt * 16 + lrow) * 8];
#pragma unroll
        for (int dt = 0; dt < 8; ++dt)
          o[dt] = MFMA_BF16(af, bfr[dt], o[dt]);
      }
      __builtin_amdgcn_s_setprio(0);
    }

    // epilogue: O / l, store to (b, s, h*128 + d) bf16
#pragma unroll
    for (int r = 0; r < 4; ++r) {
      const float inv_l = 1.f / l_i[r];
      const int row = qb * 64 + wave * 16 + quad * 4 + r;
#pragma unroll
      for (int dt = 0; dt < 8; ++dt) {
        const int d = dt * 16 + lrow;
        out[((size_t)(b * 2048 + row)) * 2048 + h * 128 + d] =
            __float2bfloat16(o[dt][r] * inv_l);
      }
    }
  }
}

// ---------------------------------------------------------------------------
// Workspace budget: 64 MiB of d_ws (round-2-proven safe).
//   d_ws:  [0, 48 MiB)  qkv; [48, 64 MiB) flex: W_qkv half, then attnout
//   d_out: [0, 16 MiB)  hidden_bf16 scratch (dead before GEMM2 rewrites)
// ---------------------------------------------------------------------------
extern "C" void kernel_launch(void* const* d_in, const int* in_sizes, int n_in,
                              void* d_out, int out_size, void* d_ws, size_t ws_size,
                              hipStream_t stream) {
  const float* hidden = (const float*)d_in[0];  // (2,2048,2048) f32
  const float* Wqkv = (const float*)d_in[1];    // (6144,2048)  f32
  const float* Wout = (const float*)d_in[2];    // (2048,2048)  f32
  float* outp = (float*)d_out;                  // (2,2048,2048) f32

  bf16* qkv = (bf16*)d_ws;                    // 48 MiB
  bf16* flex = qkv + (size_t)4096 * 6144;     // 16 MiB flex
  bf16* hbf = (bf16*)d_out;                   // d_out scratch, 16 MiB

  f32_to_bf16_kernel<<<4096, 256, 0, stream>>>(hidden, hbf, 1048576);

  f32_to_bf16_kernel<<<3072, 256, 0, stream>>>(Wqkv, flex, 786432);
  gemm_bt_async<bf16><<<dim3(24, 32), 256, 0, stream>>>(hbf, flex, qkv, 6144, 2048);
  f32_to_bf16_kernel<<<3072, 256, 0, stream>>>(Wqkv + (size_t)3072 * 2048, flex, 786432);
  gemm_bt_async<bf16><<<dim3(24, 32), 256, 0, stream>>>(hbf, flex, qkv + 3072, 6144, 2048);

  rope_kernel<<<8192, 256, 0, stream>>>(qkv);

  bf16* attnout = flex;
  attn_flash_pair<<<dim3(16, 16, 2), 256, 0, stream>>>(qkv, attnout);

  gemm_abf16_bf32<<<dim3(16, 32), 256, 0, stream>>>(attnout, Wout, outp, 2048, 2048);
}